// Round 16
// baseline (135.323 us; speedup 1.0000x reference)
//
#include <hip/hip_runtime.h>
#include <hip/hip_bf16.h>

#define DEVI __device__ __forceinline__

typedef __attribute__((ext_vector_type(8))) short bf16x8;
typedef __attribute__((ext_vector_type(4))) short bf16x4;
typedef __attribute__((ext_vector_type(4))) float f32x4;

DEVI unsigned short f2bf(float f) {
    unsigned u = __float_as_uint(f);
    u += 0x7FFF + ((u >> 16) & 1);
    return (unsigned short)(u >> 16);
}
DEVI float bf2f(unsigned short h) {
    return __uint_as_float(((unsigned)h) << 16);
}
DEVI f32x4 mfma16(bf16x8 a, bf16x8 b, f32x4 c) {
    return __builtin_amdgcn_mfma_f32_16x16x32_bf16(a, b, c, 0, 0, 0);
}
DEVI void gload_lds16(const void* g, void* l) {
    __builtin_amdgcn_global_load_lds(
        (const __attribute__((address_space(1))) unsigned int*)g,
        (__attribute__((address_space(3))) unsigned int*)l, 16, 0, 0);
}

// ---------------------------------------------------------------------------
// Fused prep: blocks [0,1024) convert X f32->bf16; [1024,1792) transpose
// W_qkv (Q-columns pre-scaled by log2(e)/32); [1792,2048) transpose W_out.
// Block 0 additionally zeroes vsum (consumed by gemm1's fused V-epilogue).
// ---------------------------------------------------------------------------
DEVI void wt_body(const float* __restrict__ W, unsigned short* __restrict__ Wt,
                  int N, int n0, int k0, float sc, int tid,
                  unsigned short (*T)[72])
{
#pragma unroll
    for (int j = 0; j < 4; ++j) {
        int idx = tid + j * 256;
        int kk = idx >> 4, c4 = (idx & 15) << 2;
        float4 v = *(const float4*)(W + (size_t)(k0 + kk) * N + n0 + c4);
        T[c4 + 0][kk] = f2bf(v.x * sc); T[c4 + 1][kk] = f2bf(v.y * sc);
        T[c4 + 2][kk] = f2bf(v.z * sc); T[c4 + 3][kk] = f2bf(v.w * sc);
    }
    __syncthreads();
#pragma unroll
    for (int j = 0; j < 4; ++j) {
        int idx = tid + j * 256;
        int n = idx >> 4, c4 = (idx & 15) << 2;
        *(bf16x4*)(Wt + (size_t)(n0 + n) * 1024 + k0 + c4) = *(bf16x4*)&T[n][c4];
    }
}

__global__ __launch_bounds__(256) void k_prep(
    const float* __restrict__ X, const float* __restrict__ Wqkv,
    const float* __restrict__ Wout,
    unsigned short* __restrict__ Xb, unsigned short* __restrict__ Wt1,
    unsigned short* __restrict__ Wt2, float* __restrict__ vsum)
{
    __shared__ unsigned short T[64][72];
    const int tid = threadIdx.x;
    const int bid = blockIdx.x;
    const float QSC = 1.4426950408889634f / 32.0f;
    if (bid < 1024) {
        if (bid == 0) {
            float4 z = (float4){0.f, 0.f, 0.f, 0.f};
            ((float4*)vsum)[tid] = z;
            ((float4*)vsum)[tid + 256] = z;
        }
        int i = bid * 256 + tid;
#pragma unroll
        for (int j = 0; j < 4; ++j) {
            int idx = i + j * 262144;
            float4 v = *(const float4*)(X + (size_t)idx * 4);
            bf16x4 hv;
            hv[0] = (short)f2bf(v.x); hv[1] = (short)f2bf(v.y);
            hv[2] = (short)f2bf(v.z); hv[3] = (short)f2bf(v.w);
            *(bf16x4*)(Xb + (size_t)idx * 4) = hv;
        }
    } else if (bid < 1792) {
        int idx = bid - 1024;
        int n0 = (idx % 48) * 64, k0 = (idx / 48) * 64;
        wt_body(Wqkv, Wt1, 3072, n0, k0, (n0 < 1024) ? QSC : 1.0f, tid, T);
    } else {
        int idx = bid - 1792;
        int n0 = (idx & 15) * 64, k0 = (idx >> 4) * 64;
        wt_body(Wout, Wt2, 1024, n0, k0, 1.0f, tid, T);
    }
}

// ---------------------------------------------------------------------------
// GEMM1: qkv[4096][3072] bf16 = Xb[4096][1024] @ Wt1^T.  Epilogue stages C
// through LDS (36 KB shared) for coalesced bf16x8 stores.  V-section blocks
// (col0>=2048) also emit vsum (from f32 acc + shfl + atomicAdd) and Vt --
// written DIRECTLY from acc registers: each lane's acc[mi][nj] holds 4
// consecutive n for fixed dv => bf16x4 stores, no LDS round trip (the R15
// LDS-transpose version was 8-way-conflicted + 64 scalar stores: +13us).
// ---------------------------------------------------------------------------
__global__ __launch_bounds__(256) void k_gemm1(
    const unsigned short* __restrict__ A, const unsigned short* __restrict__ B,
    unsigned short* __restrict__ C, unsigned short* __restrict__ Vt,
    float* __restrict__ vsum)
{
    __shared__ unsigned short Sh[18432];   // 36 KB
    unsigned short* As = Sh;
    unsigned short* Bs = Sh + 8192;
    const int tid = threadIdx.x, lane = tid & 63, wid = tid >> 6;
    const int wr = (wid >> 1) * 64, wc = (wid & 1) * 64;
    const int row0 = blockIdx.y * 128, col0 = blockIdx.x * 128;
    const int rsel = lane & 15, kgr = (lane >> 4) * 8;
    const int lr = lane >> 3, lc = (lane & 7) * 8;

    f32x4 acc[4][4];
#pragma unroll
    for (int i = 0; i < 4; ++i)
#pragma unroll
        for (int j = 0; j < 4; ++j) acc[i][j] = (f32x4){0.f, 0.f, 0.f, 0.f};

    for (int k0 = 0; k0 < 1024; k0 += 64) {
        __syncthreads();
#pragma unroll
        for (int i = 0; i < 4; ++i) {
            int rb = wid * 32 + i * 8;
            gload_lds16(A + (size_t)(row0 + rb + lr) * 1024 + k0 + lc, As + rb * 64);
            gload_lds16(B + (size_t)(col0 + rb + lr) * 1024 + k0 + lc, Bs + rb * 64);
        }
        __syncthreads();
#pragma unroll
        for (int ks = 0; ks < 2; ++ks) {
            bf16x8 a[4], b[4];
            int ko = ks * 32 + kgr;
#pragma unroll
            for (int mi = 0; mi < 4; ++mi)
                a[mi] = *(const bf16x8*)(As + (wr + mi * 16 + rsel) * 64 + ko);
#pragma unroll
            for (int nj = 0; nj < 4; ++nj)
                b[nj] = *(const bf16x8*)(Bs + (wc + nj * 16 + rsel) * 64 + ko);
#pragma unroll
            for (int mi = 0; mi < 4; ++mi)
#pragma unroll
                for (int nj = 0; nj < 4; ++nj)
                    acc[mi][nj] = mfma16(a[mi], b[nj], acc[mi][nj]);
        }
    }
    // epilogue: per-wave 64x64 C-quadrant via LDS (72-padded), coalesced store
    __syncthreads();   // all staging reads done before overwrite
    unsigned short (*wb)[72] = (unsigned short (*)[72])(Sh + wid * 4608);
    const int g4 = (lane >> 4) << 2;
#pragma unroll
    for (int mi = 0; mi < 4; ++mi)
#pragma unroll
        for (int nj = 0; nj < 4; ++nj)
#pragma unroll
            for (int r = 0; r < 4; ++r)
                wb[mi * 16 + g4 + r][nj * 16 + rsel] = f2bf(acc[mi][nj][r]);
#pragma unroll
    for (int rr = 0; rr < 8; ++rr) {
        int row = rr * 8 + (lane >> 3);
        int c8 = (lane & 7) * 8;
        bf16x8 v = *(const bf16x8*)&wb[row][c8];
        *(bf16x8*)(C + (size_t)(row0 + wr + row) * 3072 + col0 + wc + c8) = v;
    }

    // fused V-epilogue (this wave's 64-col span is exactly one head)
    if (col0 >= 2048) {
        const int b_ = row0 >> 11;
        const int n0 = (row0 & 2047) + wr;
        const int bh = b_ * 16 + ((col0 + wc - 2048) >> 6);
        // vsum from f32 acc: lane's 16 rows x 4 cols -> shfl-reduce -> atomic
#pragma unroll
        for (int nj = 0; nj < 4; ++nj) {
            float s = 0.f;
#pragma unroll
            for (int mi = 0; mi < 4; ++mi)
#pragma unroll
                for (int r = 0; r < 4; ++r) s += acc[mi][nj][r];
            s += __shfl_xor(s, 16);
            s += __shfl_xor(s, 32);
            if (lane < 16) atomicAdd(&vsum[bh * 64 + nj * 16 + rsel], s);
        }
        // Vt direct from acc: lane owns dv = nj*16+rsel; 4 consecutive n per
        // (mi): bf16x4 store at Vt[bh][dv][n0 + mi*16 + g4 .. +3]
        unsigned short* vtb = Vt + (size_t)bh * 64 * 2048 + n0 + g4;
#pragma unroll
        for (int nj = 0; nj < 4; ++nj) {
            unsigned short* vr = vtb + (size_t)(nj * 16 + rsel) * 2048;
#pragma unroll
            for (int mi = 0; mi < 4; ++mi) {
                bf16x4 hv;
#pragma unroll
                for (int r = 0; r < 4; ++r)
                    hv[r] = (short)f2bf(acc[mi][nj][r]);
                *(bf16x4*)(vr + mi * 16) = hv;
            }
        }
    }
}

// ---------------------------------------------------------------------------
// Flash attention, q-tile 128 (nq=2), grid 512, XCD swizzle. exp2-only
// softmax.  2-tile pipeline: quad-buffered K/V (80 KB LDS), one
// vmcnt(0)+barrier per PAIR of KV tiles; row-sum via ones-MFMA (matrix pipe
// is only ~26% busy -- R13 showed moving it to VALU hurts).
// ---------------------------------------------------------------------------
__global__ __launch_bounds__(256) void k_attn(
    const unsigned short* __restrict__ qkv, const unsigned short* __restrict__ Vt,
    const float* __restrict__ vsum,
    const float* __restrict__ alpha_p, const float* __restrict__ beta_p,
    const float* __restrict__ gamma_p,
    unsigned short* __restrict__ AO)
{
    __shared__ unsigned short Ks[4][64][64];   // linear, swizzled content
    __shared__ unsigned short Vs[4][64][64];   // linear, swizzled content
    __shared__ unsigned short Ps[4][32][64];   // per-wave, 16B-slot XOR swizzle
    const int tid = threadIdx.x, lane = tid & 63, wid = tid >> 6;
    // bijective XCD swizzle: nwg=512, 64 consecutive logical blocks per XCD
    const int swz = (blockIdx.x & 7) * 64 + (blockIdx.x >> 3);
    const int bh = swz >> 4, qtb = swz & 15;
    const int b = bh >> 4, h = bh & 15;
    const int q0 = qtb * 128;
    const int rsel = lane & 15, g = lane >> 4;
    const int g4 = g << 2;
    const int wq0 = wid * 32;
    const int r7 = rsel & 7;

    // Q fragments in registers (already pre-scaled by log2(e)/32 in prep)
    bf16x8 bq[2][2];
#pragma unroll
    for (int qt = 0; qt < 2; ++qt) {
        const unsigned short* qrow =
            qkv + (size_t)(b * 2048 + q0 + wq0 + qt * 16 + rsel) * 3072 + h * 64;
        bq[qt][0] = *(const bf16x8*)(qrow + g * 8);
        bq[qt][1] = *(const bf16x8*)(qrow + 32 + g * 8);
    }

    // incremental staging pointers (inverse-swizzled source slots)
    const int sr = lane >> 3;                 // 0..7 within 8-row slab
    const int ss = (lane & 7) ^ sr;           // 16B slot in global row
    const int rb0 = wid * 16, rb1 = wid * 16 + 8;
    const unsigned short* kp0 = qkv + (size_t)(b * 2048) * 3072 + 1024 + h * 64
                              + (size_t)(rb0 + sr) * 3072 + ss * 8;
    const unsigned short* kp1 = kp0 + (size_t)8 * 3072;
    const unsigned short* vp0 = Vt + (size_t)bh * 64 * 2048
                              + (size_t)(rb0 + sr) * 2048 + ss * 8;
    const unsigned short* vp1 = vp0 + (size_t)8 * 2048;
    const size_t KADV = (size_t)64 * 3072;

    f32x4 o[2][4], ol[2];
#pragma unroll
    for (int qt = 0; qt < 2; ++qt) {
#pragma unroll
        for (int dj = 0; dj < 4; ++dj) o[qt][dj] = (f32x4){0.f, 0.f, 0.f, 0.f};
        ol[qt] = (f32x4){0.f, 0.f, 0.f, 0.f};
    }
    bf16x8 ones;
#pragma unroll
    for (int e = 0; e < 8; ++e) ones[e] = (short)0x3F80;   // bf16 1.0

#define STAGE(BUF)                                                             \
    {                                                                          \
        gload_lds16(kp0, &Ks[BUF][rb0][0]);                                    \
        gload_lds16(kp1, &Ks[BUF][rb1][0]);                                    \
        gload_lds16(vp0, &Vs[BUF][rb0][0]);                                    \
        gload_lds16(vp1, &Vs[BUF][rb1][0]);                                    \
        kp0 += KADV; kp1 += KADV; vp0 += 64; vp1 += 64;                        \
    }

    // prologue: stage tiles 0,1 into bufs 0,1
    STAGE(0); STAGE(1);
    asm volatile("s_waitcnt vmcnt(0)" ::: "memory");
    __syncthreads();

#define QK(CUR, S)                                                             \
    {                                                                          \
        _Pragma("unroll")                                                      \
        for (int qt = 0; qt < 2; ++qt)                                         \
            _Pragma("unroll")                                                  \
            for (int kj = 0; kj < 4; ++kj)                                     \
                S[qt][kj] = (f32x4){0.f, 0.f, 0.f, 0.f};                       \
        __builtin_amdgcn_s_setprio(1);                                         \
        _Pragma("unroll")                                                      \
        for (int ks = 0; ks < 2; ++ks) {                                       \
            const int sl = ((ks * 4 + g) ^ r7) * 8;                            \
            bf16x8 ak[4];                                                      \
            _Pragma("unroll")                                                  \
            for (int kj = 0; kj < 4; ++kj)                                     \
                ak[kj] = *(const bf16x8*)(&Ks[CUR][kj * 16 + rsel][sl]);       \
            _Pragma("unroll")                                                  \
            for (int qt = 0; qt < 2; ++qt)                                     \
                _Pragma("unroll")                                              \
                for (int kj = 0; kj < 4; ++kj)                                 \
                    S[qt][kj] = mfma16(ak[kj], bq[qt][ks], S[qt][kj]);         \
        }                                                                      \
        __builtin_amdgcn_s_setprio(0);                                         \
    }

#define EPV(CUR, S)                                                            \
    {                                                                          \
        _Pragma("unroll")                                                      \
        for (int qt = 0; qt < 2; ++qt)                                         \
            _Pragma("unroll")                                                  \
            for (int kj = 0; kj < 4; ++kj) {                                   \
                float p0 = __builtin_amdgcn_exp2f(S[qt][kj][0]);               \
                float p1 = __builtin_amdgcn_exp2f(S[qt][kj][1]);               \
                float p2 = __builtin_amdgcn_exp2f(S[qt][kj][2]);               \
                float p3 = __builtin_amdgcn_exp2f(S[qt][kj][3]);               \
                union { __hip_bfloat162 h2[2]; uint2 u; } pk;                  \
                pk.h2[0] = __float22bfloat162_rn(make_float2(p0, p1));         \
                pk.h2[1] = __float22bfloat162_rn(make_float2(p2, p3));         \
                const int slot16 = (kj * 2 + (g >> 1)) ^ r7;                   \
                *(uint2*)(&Ps[wid][qt * 16 + rsel][slot16 * 8 + (g & 1) * 4])  \
                    = pk.u;                                                    \
            }                                                                  \
        __builtin_amdgcn_s_setprio(1);                                         \
        _Pragma("unroll")                                                      \
        for (int ks = 0; ks < 2; ++ks) {                                       \
            const int sl = ((ks * 4 + g) ^ r7) * 8;                            \
            bf16x8 pa0 = *(const bf16x8*)(&Ps[wid][rsel][sl]);                 \
            bf16x8 pa1 = *(const bf16x8*)(&Ps[wid][16 + rsel][sl]);            \
            bf16x8 vb[4];                                                      \
            _Pragma("unroll")                                                  \
            for (int dj = 0; dj < 4; ++dj)                                     \
                vb[dj] = *(const bf16x8*)(&Vs[CUR][dj * 16 + rsel][sl]);       \
            _Pragma("unroll")                                                  \
            for (int dj = 0; dj < 4; ++dj) {                                   \
                o[0][dj] = mfma16(pa0, vb[dj], o[0][dj]);                      \
                o[1][dj] = mfma16(pa1, vb[dj], o[1][dj]);                      \
            }                                                                  \
            ol[0] = mfma16(pa0, ones, ol[0]);                                  \
            ol[1] = mfma16(pa1, ones, ol[1]);                                  \
        }                                                                      \
        __builtin_amdgcn_s_setprio(0);                                         \
    }

#define PAIR(C0, C1, DOPF)                                                     \
    {                                                                          \
        f32x4 s0[2][4], s1[2][4];                                              \
        if (DOPF) { STAGE(C0 ^ 2); STAGE(C1 ^ 2); }                            \
        QK(C0, s0);                                                            \
        QK(C1, s1);                                                            \
        EPV(C0, s0);                                                           \
        EPV(C1, s1);                                                           \
        asm volatile("s_waitcnt vmcnt(0)" ::: "memory");                       \
        __syncthreads();                                                       \
    }

#pragma unroll 1
    for (int i = 0; i < 8; ++i) {
        PAIR(0, 1, true);          // tiles 4i,4i+1; prefetch 4i+2,4i+3
        PAIR(2, 3, (i < 7));       // tiles 4i+2,4i+3; prefetch 4i+4,4i+5
    }
#undef PAIR
#undef EPV
#undef QK
#undef STAGE

    // epilogue: beta*softmax + alpha*V[q] - gamma/n * vsum
    const float alpha = *alpha_p, beta = *beta_p;
    const float gn = (*gamma_p) / 2048.0f;
#pragma unroll
    for (int qt = 0; qt < 2; ++qt) {
        float linv[4];
#pragma unroll
        for (int r = 0; r < 4; ++r)
            linv[r] = beta / ol[qt][r];
#pragma unroll
        for (int dj = 0; dj < 4; ++dj)
#pragma unroll
            for (int r = 0; r < 4; ++r) {
                int qrow = q0 + wq0 + qt * 16 + g4 + r;
                int dv = dj * 16 + rsel;
                float ov = o[qt][dj][r] * linv[r];
                float vdiag = bf2f(qkv[(size_t)(b * 2048 + qrow) * 3072 + 2048 + h * 64 + dv]);
                float vs = vsum[bh * 64 + dv];
                float res = ov + alpha * vdiag - gn * vs;
                AO[(size_t)(b * 2048 + qrow) * 1024 + h * 64 + dv] = f2bf(res);
            }
    }
}

// ---------------------------------------------------------------------------
// GEMM2: out f32[4096][1024] = AO bf16 @ Wt2^T + bias.  64x64 tile,
// grid 16x64 = 1024 blocks = 4 blocks/CU.
// ---------------------------------------------------------------------------
__global__ __launch_bounds__(256) void k_gemm2(
    const unsigned short* __restrict__ A, const unsigned short* __restrict__ B,
    const float* __restrict__ bias, float* __restrict__ Out)
{
    __shared__ unsigned short As[64 * 64];
    __shared__ unsigned short Bs[64 * 64];
    const int tid = threadIdx.x, lane = tid & 63, wid = tid >> 6;
    const int wr = (wid >> 1) * 32, wc = (wid & 1) * 32;
    const int row0 = blockIdx.y * 64, col0 = blockIdx.x * 64;
    const int rsel = lane & 15, kgr = (lane >> 4) * 8;
    const int lr = lane >> 3, lc = (lane & 7) * 8;

    f32x4 acc[2][2];
#pragma unroll
    for (int i = 0; i < 2; ++i)
#pragma unroll
        for (int j = 0; j < 2; ++j) acc[i][j] = (f32x4){0.f, 0.f, 0.f, 0.f};

    for (int k0 = 0; k0 < 1024; k0 += 64) {
        __syncthreads();
#pragma unroll
        for (int i = 0; i < 2; ++i) {
            int rb = wid * 16 + i * 8;
            gload_lds16(A + (size_t)(row0 + rb + lr) * 1024 + k0 + lc, As + rb * 64);
            gload_lds16(B + (size_t)(col0 + rb + lr) * 1024 + k0 + lc, Bs + rb * 64);
        }
        __syncthreads();
#pragma unroll
        for (int ks = 0; ks < 2; ++ks) {
            bf16x8 a[2], b[2];
            int ko = ks * 32 + kgr;
#pragma unroll
            for (int mi = 0; mi < 2; ++mi)
                a[mi] = *(const bf16x8*)(As + (wr + mi * 16 + rsel) * 64 + ko);
#pragma unroll
            for (int nj = 0; nj < 2; ++nj)
                b[nj] = *(const bf16x8*)(Bs + (wc + nj * 16 + rsel) * 64 + ko);
#pragma unroll
            for (int mi = 0; mi < 2; ++mi)
#pragma unroll
                for (int nj = 0; nj < 2; ++nj)
                    acc[mi][nj] = mfma16(a[mi], b[nj], acc[mi][nj]);
        }
    }
    const int rbase = row0 + wr + ((lane >> 4) << 2);
    const int cbase = col0 + wc + rsel;
#pragma unroll
    for (int mi = 0; mi < 2; ++mi)
#pragma unroll
        for (int nj = 0; nj < 2; ++nj) {
            int gc = cbase + nj * 16;
            float bv = bias[gc];
#pragma unroll
            for (int r = 0; r < 4; ++r)
                Out[(size_t)(rbase + mi * 16 + r) * 1024 + gc] = acc[mi][nj][r] + bv;
        }
}

// ---------------------------------------------------------------------------
extern "C" void kernel_launch(void* const* d_in, const int* in_sizes, int n_in,
                              void* d_out, int out_size, void* d_ws, size_t ws_size,
                              hipStream_t stream) {
    const float* x     = (const float*)d_in[0];
    const float* Wqkv  = (const float*)d_in[1];
    const float* Wout  = (const float*)d_in[2];
    const float* bout  = (const float*)d_in[3];
    const float* alpha = (const float*)d_in[4];
    const float* beta  = (const float*)d_in[5];
    const float* gamma = (const float*)d_in[6];
    float* out = (float*)d_out;

    char* ws = (char*)d_ws;
    unsigned short* Xb  = (unsigned short*)(ws);               // 8 MB (reused as AO)
    unsigned short* Wt1 = (unsigned short*)(ws + 8388608);     // 6 MB
    unsigned short* Wt2 = (unsigned short*)(ws + 14680064);    // 2 MB
    unsigned short* qkv = (unsigned short*)(ws + 16777216);    // 24 MB
    unsigned short* Vt  = (unsigned short*)(ws + 41943040);    // 8 MB
    float* vsum         = (float*)(ws + 50331648);             // 8 KB
    unsigned short* AO  = Xb;   // Xb dead after k_gemm1

    k_prep<<<2048, 256, 0, stream>>>(x, Wqkv, Wout, Xb, Wt1, Wt2, vsum);
    k_gemm1<<<dim3(24, 32), 256, 0, stream>>>(Xb, Wt1, qkv, Vt, vsum);
    k_attn<<<512, 256, 0, stream>>>(qkv, Vt, vsum, alpha, beta, gamma, AO);
    k_gemm2<<<dim3(16, 64), 256, 0, stream>>>(AO, Wt2, bout, out);
}

// Round 17
// 132.964 us; speedup vs baseline: 1.0177x; 1.0177x over previous
//
#include <hip/hip_runtime.h>
#include <hip/hip_bf16.h>

#define DEVI __device__ __forceinline__

typedef __attribute__((ext_vector_type(8))) short bf16x8;
typedef __attribute__((ext_vector_type(4))) short bf16x4;
typedef __attribute__((ext_vector_type(4))) float f32x4;

DEVI unsigned short f2bf(float f) {
    unsigned u = __float_as_uint(f);
    u += 0x7FFF + ((u >> 16) & 1);
    return (unsigned short)(u >> 16);
}
DEVI float bf2f(unsigned short h) {
    return __uint_as_float(((unsigned)h) << 16);
}
DEVI f32x4 mfma16(bf16x8 a, bf16x8 b, f32x4 c) {
    return __builtin_amdgcn_mfma_f32_16x16x32_bf16(a, b, c, 0, 0, 0);
}
DEVI void gload_lds16(const void* g, void* l) {
    __builtin_amdgcn_global_load_lds(
        (const __attribute__((address_space(1))) unsigned int*)g,
        (__attribute__((address_space(3))) unsigned int*)l, 16, 0, 0);
}

// ---------------------------------------------------------------------------
// Fused prep: blocks [0,1024) convert X f32->bf16; [1024,1792) transpose
// W_qkv (Q-columns pre-scaled by log2(e)/32); [1792,2048) transpose W_out.
// Block 0 additionally zeroes vsum (consumed by gemm1's fused V-epilogue).
// ---------------------------------------------------------------------------
DEVI void wt_body(const float* __restrict__ W, unsigned short* __restrict__ Wt,
                  int N, int n0, int k0, float sc, int tid,
                  unsigned short (*T)[72])
{
#pragma unroll
    for (int j = 0; j < 4; ++j) {
        int idx = tid + j * 256;
        int kk = idx >> 4, c4 = (idx & 15) << 2;
        float4 v = *(const float4*)(W + (size_t)(k0 + kk) * N + n0 + c4);
        T[c4 + 0][kk] = f2bf(v.x * sc); T[c4 + 1][kk] = f2bf(v.y * sc);
        T[c4 + 2][kk] = f2bf(v.z * sc); T[c4 + 3][kk] = f2bf(v.w * sc);
    }
    __syncthreads();
#pragma unroll
    for (int j = 0; j < 4; ++j) {
        int idx = tid + j * 256;
        int n = idx >> 4, c4 = (idx & 15) << 2;
        *(bf16x4*)(Wt + (size_t)(n0 + n) * 1024 + k0 + c4) = *(bf16x4*)&T[n][c4];
    }
}

__global__ __launch_bounds__(256) void k_prep(
    const float* __restrict__ X, const float* __restrict__ Wqkv,
    const float* __restrict__ Wout,
    unsigned short* __restrict__ Xb, unsigned short* __restrict__ Wt1,
    unsigned short* __restrict__ Wt2, float* __restrict__ vsum)
{
    __shared__ unsigned short T[64][72];
    const int tid = threadIdx.x;
    const int bid = blockIdx.x;
    const float QSC = 1.4426950408889634f / 32.0f;
    if (bid < 1024) {
        if (bid == 0) {
            float4 z = (float4){0.f, 0.f, 0.f, 0.f};
            ((float4*)vsum)[tid] = z;
            ((float4*)vsum)[tid + 256] = z;
        }
        int i = bid * 256 + tid;
#pragma unroll
        for (int j = 0; j < 4; ++j) {
            int idx = i + j * 262144;
            float4 v = *(const float4*)(X + (size_t)idx * 4);
            bf16x4 hv;
            hv[0] = (short)f2bf(v.x); hv[1] = (short)f2bf(v.y);
            hv[2] = (short)f2bf(v.z); hv[3] = (short)f2bf(v.w);
            *(bf16x4*)(Xb + (size_t)idx * 4) = hv;
        }
    } else if (bid < 1792) {
        int idx = bid - 1024;
        int n0 = (idx % 48) * 64, k0 = (idx / 48) * 64;
        wt_body(Wqkv, Wt1, 3072, n0, k0, (n0 < 1024) ? QSC : 1.0f, tid, T);
    } else {
        int idx = bid - 1792;
        int n0 = (idx & 15) * 64, k0 = (idx >> 4) * 64;
        wt_body(Wout, Wt2, 1024, n0, k0, 1.0f, tid, T);
    }
}

// ---------------------------------------------------------------------------
// GEMM1: qkv[4096][3072] bf16 = Xb[4096][1024] @ Wt1^T.  Epilogue stages C
// through LDS (36 KB shared) for coalesced bf16x8 stores.  V-section blocks
// (col0>=2048) also emit Vt + vsum (fused; replaces standalone k_vt).
// Column order REVERSED so the heavier V-epilogue blocks dispatch first and
// their extra work overlaps the Q/K blocks' main loops (tail-hiding).
// ---------------------------------------------------------------------------
__global__ __launch_bounds__(256) void k_gemm1(
    const unsigned short* __restrict__ A, const unsigned short* __restrict__ B,
    unsigned short* __restrict__ C, unsigned short* __restrict__ Vt,
    float* __restrict__ vsum)
{
    __shared__ unsigned short Sh[18432];   // 36 KB
    unsigned short* As = Sh;
    unsigned short* Bs = Sh + 8192;
    const int tid = threadIdx.x, lane = tid & 63, wid = tid >> 6;
    const int wr = (wid >> 1) * 64, wc = (wid & 1) * 64;
    const int row0 = blockIdx.y * 128, col0 = (23 - blockIdx.x) * 128;
    const int rsel = lane & 15, kgr = (lane >> 4) * 8;
    const int lr = lane >> 3, lc = (lane & 7) * 8;

    f32x4 acc[4][4];
#pragma unroll
    for (int i = 0; i < 4; ++i)
#pragma unroll
        for (int j = 0; j < 4; ++j) acc[i][j] = (f32x4){0.f, 0.f, 0.f, 0.f};

    for (int k0 = 0; k0 < 1024; k0 += 64) {
        __syncthreads();
#pragma unroll
        for (int i = 0; i < 4; ++i) {
            int rb = wid * 32 + i * 8;
            gload_lds16(A + (size_t)(row0 + rb + lr) * 1024 + k0 + lc, As + rb * 64);
            gload_lds16(B + (size_t)(col0 + rb + lr) * 1024 + k0 + lc, Bs + rb * 64);
        }
        __syncthreads();
#pragma unroll
        for (int ks = 0; ks < 2; ++ks) {
            bf16x8 a[4], b[4];
            int ko = ks * 32 + kgr;
#pragma unroll
            for (int mi = 0; mi < 4; ++mi)
                a[mi] = *(const bf16x8*)(As + (wr + mi * 16 + rsel) * 64 + ko);
#pragma unroll
            for (int nj = 0; nj < 4; ++nj)
                b[nj] = *(const bf16x8*)(Bs + (wc + nj * 16 + rsel) * 64 + ko);
#pragma unroll
            for (int mi = 0; mi < 4; ++mi)
#pragma unroll
                for (int nj = 0; nj < 4; ++nj)
                    acc[mi][nj] = mfma16(a[mi], b[nj], acc[mi][nj]);
        }
    }
    // epilogue: per-wave 64x64 C-quadrant via LDS (72-padded), coalesced store
    __syncthreads();   // all staging reads done before overwrite
    unsigned short (*wb)[72] = (unsigned short (*)[72])(Sh + wid * 4608);
    const int g4 = (lane >> 4) << 2;
#pragma unroll
    for (int mi = 0; mi < 4; ++mi)
#pragma unroll
        for (int nj = 0; nj < 4; ++nj)
#pragma unroll
            for (int r = 0; r < 4; ++r)
                wb[mi * 16 + g4 + r][nj * 16 + rsel] = f2bf(acc[mi][nj][r]);
#pragma unroll
    for (int rr = 0; rr < 8; ++rr) {
        int row = rr * 8 + (lane >> 3);
        int c8 = (lane & 7) * 8;
        bf16x8 v = *(const bf16x8*)&wb[row][c8];
        *(bf16x8*)(C + (size_t)(row0 + wr + row) * 3072 + col0 + wc + c8) = v;
    }

    // fused V-epilogue (this wave's 64-col span is exactly one head)
    if (col0 >= 2048) {
        const int b_ = row0 >> 11;
        const int n0 = (row0 & 2047) + wr;
        const int bh = b_ * 16 + ((col0 + wc - 2048) >> 6);
        // vsum from f32 acc: lane's 16 rows x 4 cols -> shfl-reduce -> atomic
#pragma unroll
        for (int nj = 0; nj < 4; ++nj) {
            float s = 0.f;
#pragma unroll
            for (int mi = 0; mi < 4; ++mi)
#pragma unroll
                for (int r = 0; r < 4; ++r) s += acc[mi][nj][r];
            s += __shfl_xor(s, 16);
            s += __shfl_xor(s, 32);
            if (lane < 16) atomicAdd(&vsum[bh * 64 + nj * 16 + rsel], s);
        }
        // Vt transpose-write: lane owns n = n0+lane; walk dv columns of wb
        unsigned short* vtb = Vt + (size_t)bh * 64 * 2048 + n0 + lane;
#pragma unroll 8
        for (int dv = 0; dv < 64; ++dv)
            vtb[(size_t)dv * 2048] = wb[lane][dv];
    }
}

// ---------------------------------------------------------------------------
// Flash attention, q-tile 128 (nq=2), grid 512, XCD swizzle. exp2-only
// softmax.  2-tile pipeline: quad-buffered K/V (80 KB LDS), one
// vmcnt(0)+barrier per PAIR of KV tiles; row-sum via ones-MFMA (matrix pipe
// is only ~26% busy -- R13 showed moving it to VALU hurts).
// ---------------------------------------------------------------------------
__global__ __launch_bounds__(256) void k_attn(
    const unsigned short* __restrict__ qkv, const unsigned short* __restrict__ Vt,
    const float* __restrict__ vsum,
    const float* __restrict__ alpha_p, const float* __restrict__ beta_p,
    const float* __restrict__ gamma_p,
    unsigned short* __restrict__ AO)
{
    __shared__ unsigned short Ks[4][64][64];   // linear, swizzled content
    __shared__ unsigned short Vs[4][64][64];   // linear, swizzled content
    __shared__ unsigned short Ps[4][32][64];   // per-wave, 16B-slot XOR swizzle
    const int tid = threadIdx.x, lane = tid & 63, wid = tid >> 6;
    // bijective XCD swizzle: nwg=512, 64 consecutive logical blocks per XCD
    const int swz = (blockIdx.x & 7) * 64 + (blockIdx.x >> 3);
    const int bh = swz >> 4, qtb = swz & 15;
    const int b = bh >> 4, h = bh & 15;
    const int q0 = qtb * 128;
    const int rsel = lane & 15, g = lane >> 4;
    const int g4 = g << 2;
    const int wq0 = wid * 32;
    const int r7 = rsel & 7;

    // Q fragments in registers (already pre-scaled by log2(e)/32 in prep)
    bf16x8 bq[2][2];
#pragma unroll
    for (int qt = 0; qt < 2; ++qt) {
        const unsigned short* qrow =
            qkv + (size_t)(b * 2048 + q0 + wq0 + qt * 16 + rsel) * 3072 + h * 64;
        bq[qt][0] = *(const bf16x8*)(qrow + g * 8);
        bq[qt][1] = *(const bf16x8*)(qrow + 32 + g * 8);
    }

    // incremental staging pointers (inverse-swizzled source slots)
    const int sr = lane >> 3;                 // 0..7 within 8-row slab
    const int ss = (lane & 7) ^ sr;           // 16B slot in global row
    const int rb0 = wid * 16, rb1 = wid * 16 + 8;
    const unsigned short* kp0 = qkv + (size_t)(b * 2048) * 3072 + 1024 + h * 64
                              + (size_t)(rb0 + sr) * 3072 + ss * 8;
    const unsigned short* kp1 = kp0 + (size_t)8 * 3072;
    const unsigned short* vp0 = Vt + (size_t)bh * 64 * 2048
                              + (size_t)(rb0 + sr) * 2048 + ss * 8;
    const unsigned short* vp1 = vp0 + (size_t)8 * 2048;
    const size_t KADV = (size_t)64 * 3072;

    f32x4 o[2][4], ol[2];
#pragma unroll
    for (int qt = 0; qt < 2; ++qt) {
#pragma unroll
        for (int dj = 0; dj < 4; ++dj) o[qt][dj] = (f32x4){0.f, 0.f, 0.f, 0.f};
        ol[qt] = (f32x4){0.f, 0.f, 0.f, 0.f};
    }
    bf16x8 ones;
#pragma unroll
    for (int e = 0; e < 8; ++e) ones[e] = (short)0x3F80;   // bf16 1.0

#define STAGE(BUF)                                                             \
    {                                                                          \
        gload_lds16(kp0, &Ks[BUF][rb0][0]);                                    \
        gload_lds16(kp1, &Ks[BUF][rb1][0]);                                    \
        gload_lds16(vp0, &Vs[BUF][rb0][0]);                                    \
        gload_lds16(vp1, &Vs[BUF][rb1][0]);                                    \
        kp0 += KADV; kp1 += KADV; vp0 += 64; vp1 += 64;                        \
    }

    // prologue: stage tiles 0,1 into bufs 0,1
    STAGE(0); STAGE(1);
    asm volatile("s_waitcnt vmcnt(0)" ::: "memory");
    __syncthreads();

#define QK(CUR, S)                                                             \
    {                                                                          \
        _Pragma("unroll")                                                      \
        for (int qt = 0; qt < 2; ++qt)                                         \
            _Pragma("unroll")                                                  \
            for (int kj = 0; kj < 4; ++kj)                                     \
                S[qt][kj] = (f32x4){0.f, 0.f, 0.f, 0.f};                       \
        __builtin_amdgcn_s_setprio(1);                                         \
        _Pragma("unroll")                                                      \
        for (int ks = 0; ks < 2; ++ks) {                                       \
            const int sl = ((ks * 4 + g) ^ r7) * 8;                            \
            bf16x8 ak[4];                                                      \
            _Pragma("unroll")                                                  \
            for (int kj = 0; kj < 4; ++kj)                                     \
                ak[kj] = *(const bf16x8*)(&Ks[CUR][kj * 16 + rsel][sl]);       \
            _Pragma("unroll")                                                  \
            for (int qt = 0; qt < 2; ++qt)                                     \
                _Pragma("unroll")                                              \
                for (int kj = 0; kj < 4; ++kj)                                 \
                    S[qt][kj] = mfma16(ak[kj], bq[qt][ks], S[qt][kj]);         \
        }                                                                      \
        __builtin_amdgcn_s_setprio(0);                                         \
    }

#define EPV(CUR, S)                                                            \
    {                                                                          \
        _Pragma("unroll")                                                      \
        for (int qt = 0; qt < 2; ++qt)                                         \
            _Pragma("unroll")                                                  \
            for (int kj = 0; kj < 4; ++kj) {                                   \
                float p0 = __builtin_amdgcn_exp2f(S[qt][kj][0]);               \
                float p1 = __builtin_amdgcn_exp2f(S[qt][kj][1]);               \
                float p2 = __builtin_amdgcn_exp2f(S[qt][kj][2]);               \
                float p3 = __builtin_amdgcn_exp2f(S[qt][kj][3]);               \
                union { __hip_bfloat162 h2[2]; uint2 u; } pk;                  \
                pk.h2[0] = __float22bfloat162_rn(make_float2(p0, p1));         \
                pk.h2[1] = __float22bfloat162_rn(make_float2(p2, p3));         \
                const int slot16 = (kj * 2 + (g >> 1)) ^ r7;                   \
                *(uint2*)(&Ps[wid][qt * 16 + rsel][slot16 * 8 + (g & 1) * 4])  \
                    = pk.u;                                                    \
            }                                                                  \
        __builtin_amdgcn_s_setprio(1);                                         \
        _Pragma("unroll")                                                      \
        for (int ks = 0; ks < 2; ++ks) {                                       \
            const int sl = ((ks * 4 + g) ^ r7) * 8;                            \
            bf16x8 pa0 = *(const bf16x8*)(&Ps[wid][rsel][sl]);                 \
            bf16x8 pa1 = *(const bf16x8*)(&Ps[wid][16 + rsel][sl]);            \
            bf16x8 vb[4];                                                      \
            _Pragma("unroll")                                                  \
            for (int dj = 0; dj < 4; ++dj)                                     \
                vb[dj] = *(const bf16x8*)(&Vs[CUR][dj * 16 + rsel][sl]);       \
            _Pragma("unroll")                                                  \
            for (int dj = 0; dj < 4; ++dj) {                                   \
                o[0][dj] = mfma16(pa0, vb[dj], o[0][dj]);                      \
                o[1][dj] = mfma16(pa1, vb[dj], o[1][dj]);                      \
            }                                                                  \
            ol[0] = mfma16(pa0, ones, ol[0]);                                  \
            ol[1] = mfma16(pa1, ones, ol[1]);                                  \
        }                                                                      \
        __builtin_amdgcn_s_setprio(0);                                         \
    }

#define PAIR(C0, C1, DOPF)                                                     \
    {                                                                          \
        f32x4 s0[2][4], s1[2][4];                                              \
        if (DOPF) { STAGE(C0 ^ 2); STAGE(C1 ^ 2); }                            \
        QK(C0, s0);                                                            \
        QK(C1, s1);                                                            \
        EPV(C0, s0);                                                           \
        EPV(C1, s1);                                                           \
        asm volatile("s_waitcnt vmcnt(0)" ::: "memory");                       \
        __syncthreads();                                                       \
    }

#pragma unroll 1
    for (int i = 0; i < 8; ++i) {
        PAIR(0, 1, true);          // tiles 4i,4i+1; prefetch 4i+2,4i+3
        PAIR(2, 3, (i < 7));       // tiles 4i+2,4i+3; prefetch 4i+4,4i+5
    }
#undef PAIR
#undef EPV
#undef QK
#undef STAGE

    // epilogue: beta*softmax + alpha*V[q] - gamma/n * vsum
    const float alpha = *alpha_p, beta = *beta_p;
    const float gn = (*gamma_p) / 2048.0f;
#pragma unroll
    for (int qt = 0; qt < 2; ++qt) {
        float linv[4];
#pragma unroll
        for (int r = 0; r < 4; ++r)
            linv[r] = beta / ol[qt][r];
#pragma unroll
        for (int dj = 0; dj < 4; ++dj)
#pragma unroll
            for (int r = 0; r < 4; ++r) {
                int qrow = q0 + wq0 + qt * 16 + g4 + r;
                int dv = dj * 16 + rsel;
                float ov = o[qt][dj][r] * linv[r];
                float vdiag = bf2f(qkv[(size_t)(b * 2048 + qrow) * 3072 + 2048 + h * 64 + dv]);
                float vs = vsum[bh * 64 + dv];
                float res = ov + alpha * vdiag - gn * vs;
                AO[(size_t)(b * 2048 + qrow) * 1024 + h * 64 + dv] = f2bf(res);
            }
    }
}

// ---------------------------------------------------------------------------
// GEMM2: out f32[4096][1024] = AO bf16 @ Wt2^T + bias.  64x64 tile,
// grid 16x64 = 1024 blocks = 4 blocks/CU.
// ---------------------------------------------------------------------------
__global__ __launch_bounds__(256) void k_gemm2(
    const unsigned short* __restrict__ A, const unsigned short* __restrict__ B,
    const float* __restrict__ bias, float* __restrict__ Out)
{
    __shared__ unsigned short As[64 * 64];
    __shared__ unsigned short Bs[64 * 64];
    const int tid = threadIdx.x, lane = tid & 63, wid = tid >> 6;
    const int wr = (wid >> 1) * 32, wc = (wid & 1) * 32;
    const int row0 = blockIdx.y * 64, col0 = blockIdx.x * 64;
    const int rsel = lane & 15, kgr = (lane >> 4) * 8;
    const int lr = lane >> 3, lc = (lane & 7) * 8;

    f32x4 acc[2][2];
#pragma unroll
    for (int i = 0; i < 2; ++i)
#pragma unroll
        for (int j = 0; j < 2; ++j) acc[i][j] = (f32x4){0.f, 0.f, 0.f, 0.f};

    for (int k0 = 0; k0 < 1024; k0 += 64) {
        __syncthreads();
#pragma unroll
        for (int i = 0; i < 2; ++i) {
            int rb = wid * 16 + i * 8;
            gload_lds16(A + (size_t)(row0 + rb + lr) * 1024 + k0 + lc, As + rb * 64);
            gload_lds16(B + (size_t)(col0 + rb + lr) * 1024 + k0 + lc, Bs + rb * 64);
        }
        __syncthreads();
#pragma unroll
        for (int ks = 0; ks < 2; ++ks) {
            bf16x8 a[2], b[2];
            int ko = ks * 32 + kgr;
#pragma unroll
            for (int mi = 0; mi < 2; ++mi)
                a[mi] = *(const bf16x8*)(As + (wr + mi * 16 + rsel) * 64 + ko);
#pragma unroll
            for (int nj = 0; nj < 2; ++nj)
                b[nj] = *(const bf16x8*)(Bs + (wc + nj * 16 + rsel) * 64 + ko);
#pragma unroll
            for (int mi = 0; mi < 2; ++mi)
#pragma unroll
                for (int nj = 0; nj < 2; ++nj)
                    acc[mi][nj] = mfma16(a[mi], b[nj], acc[mi][nj]);
        }
    }
    const int rbase = row0 + wr + ((lane >> 4) << 2);
    const int cbase = col0 + wc + rsel;
#pragma unroll
    for (int mi = 0; mi < 2; ++mi)
#pragma unroll
        for (int nj = 0; nj < 2; ++nj) {
            int gc = cbase + nj * 16;
            float bv = bias[gc];
#pragma unroll
            for (int r = 0; r < 4; ++r)
                Out[(size_t)(rbase + mi * 16 + r) * 1024 + gc] = acc[mi][nj][r] + bv;
        }
}

// ---------------------------------------------------------------------------
extern "C" void kernel_launch(void* const* d_in, const int* in_sizes, int n_in,
                              void* d_out, int out_size, void* d_ws, size_t ws_size,
                              hipStream_t stream) {
    const float* x     = (const float*)d_in[0];
    const float* Wqkv  = (const float*)d_in[1];
    const float* Wout  = (const float*)d_in[2];
    const float* bout  = (const float*)d_in[3];
    const float* alpha = (const float*)d_in[4];
    const float* beta  = (const float*)d_in[5];
    const float* gamma = (const float*)d_in[6];
    float* out = (float*)d_out;

    char* ws = (char*)d_ws;
    unsigned short* Xb  = (unsigned short*)(ws);               // 8 MB (reused as AO)
    unsigned short* Wt1 = (unsigned short*)(ws + 8388608);     // 6 MB
    unsigned short* Wt2 = (unsigned short*)(ws + 14680064);    // 2 MB
    unsigned short* qkv = (unsigned short*)(ws + 16777216);    // 24 MB
    unsigned short* Vt  = (unsigned short*)(ws + 41943040);    // 8 MB
    float* vsum         = (float*)(ws + 50331648);             // 8 KB
    unsigned short* AO  = Xb;   // Xb dead after k_gemm1

    k_prep<<<2048, 256, 0, stream>>>(x, Wqkv, Wout, Xb, Wt1, Wt2, vsum);
    k_gemm1<<<dim3(24, 32), 256, 0, stream>>>(Xb, Wt1, qkv, Vt, vsum);
    k_attn<<<512, 256, 0, stream>>>(qkv, Vt, vsum, alpha, beta, gamma, AO);
    k_gemm2<<<dim3(16, 64), 256, 0, stream>>>(AO, Wt2, bout, out);
}

// Round 18
// 122.000 us; speedup vs baseline: 1.1092x; 1.0899x over previous
//
#include <hip/hip_runtime.h>
#include <hip/hip_bf16.h>

#define DEVI __device__ __forceinline__

typedef __attribute__((ext_vector_type(8))) short bf16x8;
typedef __attribute__((ext_vector_type(4))) short bf16x4;
typedef __attribute__((ext_vector_type(4))) float f32x4;

DEVI unsigned short f2bf(float f) {
    unsigned u = __float_as_uint(f);
    u += 0x7FFF + ((u >> 16) & 1);
    return (unsigned short)(u >> 16);
}
DEVI float bf2f(unsigned short h) {
    return __uint_as_float(((unsigned)h) << 16);
}
DEVI f32x4 mfma16(bf16x8 a, bf16x8 b, f32x4 c) {
    return __builtin_amdgcn_mfma_f32_16x16x32_bf16(a, b, c, 0, 0, 0);
}
DEVI void gload_lds16(const void* g, void* l) {
    __builtin_amdgcn_global_load_lds(
        (const __attribute__((address_space(1))) unsigned int*)g,
        (__attribute__((address_space(3))) unsigned int*)l, 16, 0, 0);
}

// ---------------------------------------------------------------------------
// Fused prep: blocks [0,1024) convert X f32->bf16; [1024,1792) transpose
// W_qkv (Q-columns pre-scaled by log2(e)/32); [1792,2048) transpose W_out.
// Block 0 additionally zeroes vsum (consumed by gemm1's fused V-epilogue).
// ---------------------------------------------------------------------------
DEVI void wt_body(const float* __restrict__ W, unsigned short* __restrict__ Wt,
                  int N, int n0, int k0, float sc, int tid,
                  unsigned short (*T)[72])
{
#pragma unroll
    for (int j = 0; j < 4; ++j) {
        int idx = tid + j * 256;
        int kk = idx >> 4, c4 = (idx & 15) << 2;
        float4 v = *(const float4*)(W + (size_t)(k0 + kk) * N + n0 + c4);
        T[c4 + 0][kk] = f2bf(v.x * sc); T[c4 + 1][kk] = f2bf(v.y * sc);
        T[c4 + 2][kk] = f2bf(v.z * sc); T[c4 + 3][kk] = f2bf(v.w * sc);
    }
    __syncthreads();
#pragma unroll
    for (int j = 0; j < 4; ++j) {
        int idx = tid + j * 256;
        int n = idx >> 4, c4 = (idx & 15) << 2;
        *(bf16x4*)(Wt + (size_t)(n0 + n) * 1024 + k0 + c4) = *(bf16x4*)&T[n][c4];
    }
}

__global__ __launch_bounds__(256) void k_prep(
    const float* __restrict__ X, const float* __restrict__ Wqkv,
    const float* __restrict__ Wout,
    unsigned short* __restrict__ Xb, unsigned short* __restrict__ Wt1,
    unsigned short* __restrict__ Wt2, float* __restrict__ vsum)
{
    __shared__ unsigned short T[64][72];
    const int tid = threadIdx.x;
    const int bid = blockIdx.x;
    const float QSC = 1.4426950408889634f / 32.0f;
    if (bid < 1024) {
        if (bid == 0) {
            float4 z = (float4){0.f, 0.f, 0.f, 0.f};
            ((float4*)vsum)[tid] = z;
            ((float4*)vsum)[tid + 256] = z;
        }
        int i = bid * 256 + tid;
#pragma unroll
        for (int j = 0; j < 4; ++j) {
            int idx = i + j * 262144;
            float4 v = *(const float4*)(X + (size_t)idx * 4);
            bf16x4 hv;
            hv[0] = (short)f2bf(v.x); hv[1] = (short)f2bf(v.y);
            hv[2] = (short)f2bf(v.z); hv[3] = (short)f2bf(v.w);
            *(bf16x4*)(Xb + (size_t)idx * 4) = hv;
        }
    } else if (bid < 1792) {
        int idx = bid - 1024;
        int n0 = (idx % 48) * 64, k0 = (idx / 48) * 64;
        wt_body(Wqkv, Wt1, 3072, n0, k0, (n0 < 1024) ? QSC : 1.0f, tid, T);
    } else {
        int idx = bid - 1792;
        int n0 = (idx & 15) * 64, k0 = (idx >> 4) * 64;
        wt_body(Wout, Wt2, 1024, n0, k0, 1.0f, tid, T);
    }
}

// ---------------------------------------------------------------------------
// GEMM1: qkv[4096][3072] bf16 = Xb[4096][1024] @ Wt1^T.  Double-buffered
// gload_lds staging (64 KB LDS): prefetch k+1 issued BEFORE compute of k,
// one vmcnt(0)+barrier per K-step (was barrier;stage;barrier;compute --
// load latency fully exposed).  Epilogue stages C through LDS (aliases the
// staging buffers) for coalesced bf16x8 stores.  V-section blocks
// (col0>=2048) also emit Vt + vsum (fused; replaces standalone k_vt).
// ---------------------------------------------------------------------------
__global__ __launch_bounds__(256) void k_gemm1(
    const unsigned short* __restrict__ A, const unsigned short* __restrict__ B,
    unsigned short* __restrict__ C, unsigned short* __restrict__ Vt,
    float* __restrict__ vsum)
{
    __shared__ unsigned short Sh[32768];   // 64 KB: [buf][A 8192 | B 8192]
    const int tid = threadIdx.x, lane = tid & 63, wid = tid >> 6;
    const int wr = (wid >> 1) * 64, wc = (wid & 1) * 64;
    const int row0 = blockIdx.y * 128, col0 = (23 - blockIdx.x) * 128;
    const int rsel = lane & 15, kgr = (lane >> 4) * 8;
    const int lr = lane >> 3, lc = (lane & 7) * 8;

    f32x4 acc[4][4];
#pragma unroll
    for (int i = 0; i < 4; ++i)
#pragma unroll
        for (int j = 0; j < 4; ++j) acc[i][j] = (f32x4){0.f, 0.f, 0.f, 0.f};

    // incremental staging pointers: wave wid covers rows wid*32 .. wid*32+31
    const unsigned short* ap[4];
    const unsigned short* bp[4];
#pragma unroll
    for (int i = 0; i < 4; ++i) {
        ap[i] = A + (size_t)(row0 + wid * 32 + i * 8 + lr) * 1024 + lc;
        bp[i] = B + (size_t)(col0 + wid * 32 + i * 8 + lr) * 1024 + lc;
    }

#define GSTAGE(BUF)                                                            \
    {                                                                          \
        _Pragma("unroll")                                                      \
        for (int i = 0; i < 4; ++i) {                                          \
            int rb = wid * 32 + i * 8;                                         \
            gload_lds16(ap[i], Sh + (BUF) * 16384 + rb * 64);                  \
            gload_lds16(bp[i], Sh + (BUF) * 16384 + 8192 + rb * 64);           \
            ap[i] += 64; bp[i] += 64;                                          \
        }                                                                      \
    }

#define GCOMP(CUR)                                                             \
    {                                                                          \
        const unsigned short* As_ = Sh + (CUR) * 16384;                        \
        const unsigned short* Bs_ = As_ + 8192;                                \
        _Pragma("unroll")                                                      \
        for (int ks = 0; ks < 2; ++ks) {                                       \
            bf16x8 a[4], b[4];                                                 \
            int ko = ks * 32 + kgr;                                            \
            _Pragma("unroll")                                                  \
            for (int mi = 0; mi < 4; ++mi)                                     \
                a[mi] = *(const bf16x8*)(As_ + (wr + mi * 16 + rsel) * 64 + ko);\
            _Pragma("unroll")                                                  \
            for (int nj = 0; nj < 4; ++nj)                                     \
                b[nj] = *(const bf16x8*)(Bs_ + (wc + nj * 16 + rsel) * 64 + ko);\
            _Pragma("unroll")                                                  \
            for (int mi = 0; mi < 4; ++mi)                                     \
                _Pragma("unroll")                                              \
                for (int nj = 0; nj < 4; ++nj)                                 \
                    acc[mi][nj] = mfma16(a[mi], b[nj], acc[mi][nj]);           \
        }                                                                      \
    }

#define GBODY(CUR, DOPF)                                                       \
    {                                                                          \
        if (DOPF) GSTAGE((CUR) ^ 1);                                           \
        GCOMP(CUR);                                                            \
        asm volatile("s_waitcnt vmcnt(0)" ::: "memory");                       \
        __syncthreads();                                                       \
    }

    GSTAGE(0);
    asm volatile("s_waitcnt vmcnt(0)" ::: "memory");
    __syncthreads();
#pragma unroll 1
    for (int i = 0; i < 8; ++i) {
        GBODY(0, true);
        GBODY(1, (i < 7));
    }
#undef GBODY
#undef GCOMP
#undef GSTAGE

    // epilogue: per-wave 64x64 C-quadrant via LDS (72-padded), coalesced store
    __syncthreads();   // all staging reads done before overwrite
    unsigned short (*wb)[72] = (unsigned short (*)[72])(Sh + wid * 4608);
    const int g4 = (lane >> 4) << 2;
#pragma unroll
    for (int mi = 0; mi < 4; ++mi)
#pragma unroll
        for (int nj = 0; nj < 4; ++nj)
#pragma unroll
            for (int r = 0; r < 4; ++r)
                wb[mi * 16 + g4 + r][nj * 16 + rsel] = f2bf(acc[mi][nj][r]);
#pragma unroll
    for (int rr = 0; rr < 8; ++rr) {
        int row = rr * 8 + (lane >> 3);
        int c8 = (lane & 7) * 8;
        bf16x8 v = *(const bf16x8*)&wb[row][c8];
        *(bf16x8*)(C + (size_t)(row0 + wr + row) * 3072 + col0 + wc + c8) = v;
    }

    // fused V-epilogue (this wave's 64-col span is exactly one head)
    if (col0 >= 2048) {
        const int b_ = row0 >> 11;
        const int n0 = (row0 & 2047) + wr;
        const int bh = b_ * 16 + ((col0 + wc - 2048) >> 6);
        // vsum from f32 acc: lane's 16 rows x 4 cols -> shfl-reduce -> atomic
#pragma unroll
        for (int nj = 0; nj < 4; ++nj) {
            float s = 0.f;
#pragma unroll
            for (int mi = 0; mi < 4; ++mi)
#pragma unroll
                for (int r = 0; r < 4; ++r) s += acc[mi][nj][r];
            s += __shfl_xor(s, 16);
            s += __shfl_xor(s, 32);
            if (lane < 16) atomicAdd(&vsum[bh * 64 + nj * 16 + rsel], s);
        }
        // Vt transpose-write: lane owns n = n0+lane; walk dv columns of wb
        unsigned short* vtb = Vt + (size_t)bh * 64 * 2048 + n0 + lane;
#pragma unroll 8
        for (int dv = 0; dv < 64; ++dv)
            vtb[(size_t)dv * 2048] = wb[lane][dv];
    }
}

// ---------------------------------------------------------------------------
// Flash attention, q-tile 128 (nq=2), grid 512, XCD swizzle. exp2-only
// softmax.  2-tile pipeline: quad-buffered K/V (80 KB LDS), one
// vmcnt(0)+barrier per PAIR of KV tiles; row-sum via ones-MFMA (matrix pipe
// is only ~26% busy -- R13 showed moving it to VALU hurts).
// ---------------------------------------------------------------------------
__global__ __launch_bounds__(256) void k_attn(
    const unsigned short* __restrict__ qkv, const unsigned short* __restrict__ Vt,
    const float* __restrict__ vsum,
    const float* __restrict__ alpha_p, const float* __restrict__ beta_p,
    const float* __restrict__ gamma_p,
    unsigned short* __restrict__ AO)
{
    __shared__ unsigned short Ks[4][64][64];   // linear, swizzled content
    __shared__ unsigned short Vs[4][64][64];   // linear, swizzled content
    __shared__ unsigned short Ps[4][32][64];   // per-wave, 16B-slot XOR swizzle
    const int tid = threadIdx.x, lane = tid & 63, wid = tid >> 6;
    // bijective XCD swizzle: nwg=512, 64 consecutive logical blocks per XCD
    const int swz = (blockIdx.x & 7) * 64 + (blockIdx.x >> 3);
    const int bh = swz >> 4, qtb = swz & 15;
    const int b = bh >> 4, h = bh & 15;
    const int q0 = qtb * 128;
    const int rsel = lane & 15, g = lane >> 4;
    const int g4 = g << 2;
    const int wq0 = wid * 32;
    const int r7 = rsel & 7;

    // Q fragments in registers (already pre-scaled by log2(e)/32 in prep)
    bf16x8 bq[2][2];
#pragma unroll
    for (int qt = 0; qt < 2; ++qt) {
        const unsigned short* qrow =
            qkv + (size_t)(b * 2048 + q0 + wq0 + qt * 16 + rsel) * 3072 + h * 64;
        bq[qt][0] = *(const bf16x8*)(qrow + g * 8);
        bq[qt][1] = *(const bf16x8*)(qrow + 32 + g * 8);
    }

    // incremental staging pointers (inverse-swizzled source slots)
    const int sr = lane >> 3;                 // 0..7 within 8-row slab
    const int ss = (lane & 7) ^ sr;           // 16B slot in global row
    const int rb0 = wid * 16, rb1 = wid * 16 + 8;
    const unsigned short* kp0 = qkv + (size_t)(b * 2048) * 3072 + 1024 + h * 64
                              + (size_t)(rb0 + sr) * 3072 + ss * 8;
    const unsigned short* kp1 = kp0 + (size_t)8 * 3072;
    const unsigned short* vp0 = Vt + (size_t)bh * 64 * 2048
                              + (size_t)(rb0 + sr) * 2048 + ss * 8;
    const unsigned short* vp1 = vp0 + (size_t)8 * 2048;
    const size_t KADV = (size_t)64 * 3072;

    f32x4 o[2][4], ol[2];
#pragma unroll
    for (int qt = 0; qt < 2; ++qt) {
#pragma unroll
        for (int dj = 0; dj < 4; ++dj) o[qt][dj] = (f32x4){0.f, 0.f, 0.f, 0.f};
        ol[qt] = (f32x4){0.f, 0.f, 0.f, 0.f};
    }
    bf16x8 ones;
#pragma unroll
    for (int e = 0; e < 8; ++e) ones[e] = (short)0x3F80;   // bf16 1.0

#define STAGE(BUF)                                                             \
    {                                                                          \
        gload_lds16(kp0, &Ks[BUF][rb0][0]);                                    \
        gload_lds16(kp1, &Ks[BUF][rb1][0]);                                    \
        gload_lds16(vp0, &Vs[BUF][rb0][0]);                                    \
        gload_lds16(vp1, &Vs[BUF][rb1][0]);                                    \
        kp0 += KADV; kp1 += KADV; vp0 += 64; vp1 += 64;                        \
    }

    // prologue: stage tiles 0,1 into bufs 0,1
    STAGE(0); STAGE(1);
    asm volatile("s_waitcnt vmcnt(0)" ::: "memory");
    __syncthreads();

#define QK(CUR, S)                                                             \
    {                                                                          \
        _Pragma("unroll")                                                      \
        for (int qt = 0; qt < 2; ++qt)                                         \
            _Pragma("unroll")                                                  \
            for (int kj = 0; kj < 4; ++kj)                                     \
                S[qt][kj] = (f32x4){0.f, 0.f, 0.f, 0.f};                       \
        __builtin_amdgcn_s_setprio(1);                                         \
        _Pragma("unroll")                                                      \
        for (int ks = 0; ks < 2; ++ks) {                                       \
            const int sl = ((ks * 4 + g) ^ r7) * 8;                            \
            bf16x8 ak[4];                                                      \
            _Pragma("unroll")                                                  \
            for (int kj = 0; kj < 4; ++kj)                                     \
                ak[kj] = *(const bf16x8*)(&Ks[CUR][kj * 16 + rsel][sl]);       \
            _Pragma("unroll")                                                  \
            for (int qt = 0; qt < 2; ++qt)                                     \
                _Pragma("unroll")                                              \
                for (int kj = 0; kj < 4; ++kj)                                 \
                    S[qt][kj] = mfma16(ak[kj], bq[qt][ks], S[qt][kj]);         \
        }                                                                      \
        __builtin_amdgcn_s_setprio(0);                                         \
    }

#define EPV(CUR, S)                                                            \
    {                                                                          \
        _Pragma("unroll")                                                      \
        for (int qt = 0; qt < 2; ++qt)                                         \
            _Pragma("unroll")                                                  \
            for (int kj = 0; kj < 4; ++kj) {                                   \
                float p0 = __builtin_amdgcn_exp2f(S[qt][kj][0]);               \
                float p1 = __builtin_amdgcn_exp2f(S[qt][kj][1]);               \
                float p2 = __builtin_amdgcn_exp2f(S[qt][kj][2]);               \
                float p3 = __builtin_amdgcn_exp2f(S[qt][kj][3]);               \
                union { __hip_bfloat162 h2[2]; uint2 u; } pk;                  \
                pk.h2[0] = __float22bfloat162_rn(make_float2(p0, p1));         \
                pk.h2[1] = __float22bfloat162_rn(make_float2(p2, p3));         \
                const int slot16 = (kj * 2 + (g >> 1)) ^ r7;                   \
                *(uint2*)(&Ps[wid][qt * 16 + rsel][slot16 * 8 + (g & 1) * 4])  \
                    = pk.u;                                                    \
            }                                                                  \
        __builtin_amdgcn_s_setprio(1);                                         \
        _Pragma("unroll")                                                      \
        for (int ks = 0; ks < 2; ++ks) {                                       \
            const int sl = ((ks * 4 + g) ^ r7) * 8;                            \
            bf16x8 pa0 = *(const bf16x8*)(&Ps[wid][rsel][sl]);                 \
            bf16x8 pa1 = *(const bf16x8*)(&Ps[wid][16 + rsel][sl]);            \
            bf16x8 vb[4];                                                      \
            _Pragma("unroll")                                                  \
            for (int dj = 0; dj < 4; ++dj)                                     \
                vb[dj] = *(const bf16x8*)(&Vs[CUR][dj * 16 + rsel][sl]);       \
            _Pragma("unroll")                                                  \
            for (int dj = 0; dj < 4; ++dj) {                                   \
                o[0][dj] = mfma16(pa0, vb[dj], o[0][dj]);                      \
                o[1][dj] = mfma16(pa1, vb[dj], o[1][dj]);                      \
            }                                                                  \
            ol[0] = mfma16(pa0, ones, ol[0]);                                  \
            ol[1] = mfma16(pa1, ones, ol[1]);                                  \
        }                                                                      \
        __builtin_amdgcn_s_setprio(0);                                         \
    }

#define PAIR(C0, C1, DOPF)                                                     \
    {                                                                          \
        f32x4 s0[2][4], s1[2][4];                                              \
        if (DOPF) { STAGE(C0 ^ 2); STAGE(C1 ^ 2); }                            \
        QK(C0, s0);                                                            \
        QK(C1, s1);                                                            \
        EPV(C0, s0);                                                           \
        EPV(C1, s1);                                                           \
        asm volatile("s_waitcnt vmcnt(0)" ::: "memory");                       \
        __syncthreads();                                                       \
    }

#pragma unroll 1
    for (int i = 0; i < 8; ++i) {
        PAIR(0, 1, true);          // tiles 4i,4i+1; prefetch 4i+2,4i+3
        PAIR(2, 3, (i < 7));       // tiles 4i+2,4i+3; prefetch 4i+4,4i+5
    }
#undef PAIR
#undef EPV
#undef QK
#undef STAGE

    // epilogue: beta*softmax + alpha*V[q] - gamma/n * vsum
    const float alpha = *alpha_p, beta = *beta_p;
    const float gn = (*gamma_p) / 2048.0f;
#pragma unroll
    for (int qt = 0; qt < 2; ++qt) {
        float linv[4];
#pragma unroll
        for (int r = 0; r < 4; ++r)
            linv[r] = beta / ol[qt][r];
#pragma unroll
        for (int dj = 0; dj < 4; ++dj)
#pragma unroll
            for (int r = 0; r < 4; ++r) {
                int qrow = q0 + wq0 + qt * 16 + g4 + r;
                int dv = dj * 16 + rsel;
                float ov = o[qt][dj][r] * linv[r];
                float vdiag = bf2f(qkv[(size_t)(b * 2048 + qrow) * 3072 + 2048 + h * 64 + dv]);
                float vs = vsum[bh * 64 + dv];
                float res = ov + alpha * vdiag - gn * vs;
                AO[(size_t)(b * 2048 + qrow) * 1024 + h * 64 + dv] = f2bf(res);
            }
    }
}

// ---------------------------------------------------------------------------
// GEMM2: out f32[4096][1024] = AO bf16 @ Wt2^T + bias.  64x64 tile,
// grid 16x64 = 1024 blocks = 4 blocks/CU.  Double-buffered staging (32 KB).
// ---------------------------------------------------------------------------
__global__ __launch_bounds__(256) void k_gemm2(
    const unsigned short* __restrict__ A, const unsigned short* __restrict__ B,
    const float* __restrict__ bias, float* __restrict__ Out)
{
    __shared__ unsigned short Sh[16384];   // 32 KB: [buf][A 4096 | B 4096]
    const int tid = threadIdx.x, lane = tid & 63, wid = tid >> 6;
    const int wr = (wid >> 1) * 32, wc = (wid & 1) * 32;
    const int row0 = blockIdx.y * 64, col0 = blockIdx.x * 64;
    const int rsel = lane & 15, kgr = (lane >> 4) * 8;
    const int lr = lane >> 3, lc = (lane & 7) * 8;

    f32x4 acc[2][2];
#pragma unroll
    for (int i = 0; i < 2; ++i)
#pragma unroll
        for (int j = 0; j < 2; ++j) acc[i][j] = (f32x4){0.f, 0.f, 0.f, 0.f};

    const unsigned short* ap[2];
    const unsigned short* bp[2];
#pragma unroll
    for (int i = 0; i < 2; ++i) {
        ap[i] = A + (size_t)(row0 + wid * 16 + i * 8 + lr) * 1024 + lc;
        bp[i] = B + (size_t)(col0 + wid * 16 + i * 8 + lr) * 1024 + lc;
    }

#define G2STAGE(BUF)                                                           \
    {                                                                          \
        _Pragma("unroll")                                                      \
        for (int i = 0; i < 2; ++i) {                                          \
            int rb = wid * 16 + i * 8;                                         \
            gload_lds16(ap[i], Sh + (BUF) * 8192 + rb * 64);                   \
            gload_lds16(bp[i], Sh + (BUF) * 8192 + 4096 + rb * 64);            \
            ap[i] += 64; bp[i] += 64;                                          \
        }                                                                      \
    }

#define G2BODY(CUR, DOPF)                                                      \
    {                                                                          \
        if (DOPF) G2STAGE((CUR) ^ 1);                                          \
        const unsigned short* As_ = Sh + (CUR) * 8192;                         \
        const unsigned short* Bs_ = As_ + 4096;                                \
        _Pragma("unroll")                                                      \
        for (int ks = 0; ks < 2; ++ks) {                                       \
            bf16x8 a[2], b[2];                                                 \
            int ko = ks * 32 + kgr;                                            \
            _Pragma("unroll")                                                  \
            for (int mi = 0; mi < 2; ++mi)                                     \
                a[mi] = *(const bf16x8*)(As_ + (wr + mi * 16 + rsel) * 64 + ko);\
            _Pragma("unroll")                                                  \
            for (int nj = 0; nj < 2; ++nj)                                     \
                b[nj] = *(const bf16x8*)(Bs_ + (wc + nj * 16 + rsel) * 64 + ko);\
            _Pragma("unroll")                                                  \
            for (int mi = 0; mi < 2; ++mi)                                     \
                _Pragma("unroll")                                              \
                for (int nj = 0; nj < 2; ++nj)                                 \
                    acc[mi][nj] = mfma16(a[mi], b[nj], acc[mi][nj]);           \
        }                                                                      \
        asm volatile("s_waitcnt vmcnt(0)" ::: "memory");                       \
        __syncthreads();                                                       \
    }

    G2STAGE(0);
    asm volatile("s_waitcnt vmcnt(0)" ::: "memory");
    __syncthreads();
#pragma unroll 1
    for (int i = 0; i < 8; ++i) {
        G2BODY(0, true);
        G2BODY(1, (i < 7));
    }
#undef G2BODY
#undef G2STAGE

    const int rbase = row0 + wr + ((lane >> 4) << 2);
    const int cbase = col0 + wc + rsel;
#pragma unroll
    for (int mi = 0; mi < 2; ++mi)
#pragma unroll
        for (int nj = 0; nj < 2; ++nj) {
            int gc = cbase + nj * 16;
            float bv = bias[gc];
#pragma unroll
            for (int r = 0; r < 4; ++r)
                Out[(size_t)(rbase + mi * 16 + r) * 1024 + gc] = acc[mi][nj][r] + bv;
        }
}

// ---------------------------------------------------------------------------
extern "C" void kernel_launch(void* const* d_in, const int* in_sizes, int n_in,
                              void* d_out, int out_size, void* d_ws, size_t ws_size,
                              hipStream_t stream) {
    const float* x     = (const float*)d_in[0];
    const float* Wqkv  = (const float*)d_in[1];
    const float* Wout  = (const float*)d_in[2];
    const float* bout  = (const float*)d_in[3];
    const float* alpha = (const float*)d_in[4];
    const float* beta  = (const float*)d_in[5];
    const float* gamma = (const float*)d_in[6];
    float* out = (float*)d_out;

    char* ws = (char*)d_ws;
    unsigned short* Xb  = (unsigned short*)(ws);               // 8 MB (reused as AO)
    unsigned short* Wt1 = (unsigned short*)(ws + 8388608);     // 6 MB
    unsigned short* Wt2 = (unsigned short*)(ws + 14680064);    // 2 MB
    unsigned short* qkv = (unsigned short*)(ws + 16777216);    // 24 MB
    unsigned short* Vt  = (unsigned short*)(ws + 41943040);    // 8 MB
    float* vsum         = (float*)(ws + 50331648);             // 8 KB
    unsigned short* AO  = Xb;   // Xb dead after k_gemm1

    k_prep<<<2048, 256, 0, stream>>>(x, Wqkv, Wout, Xb, Wt1, Wt2, vsum);
    k_gemm1<<<dim3(24, 32), 256, 0, stream>>>(Xb, Wt1, qkv, Vt, vsum);
    k_attn<<<512, 256, 0, stream>>>(qkv, Vt, vsum, alpha, beta, gamma, AO);
    k_gemm2<<<dim3(16, 64), 256, 0, stream>>>(AO, Wt2, bout, out);
}